// Round 1
// baseline (212.314 us; speedup 1.0000x reference)
//
#include <hip/hip_runtime.h>
#include <math.h>

#define V 32768
#define D 15
#define DM 1024
#define B 8
#define T 1024
#define NNODES (V - 1)  // 32767

// Kernel 1: sig[v*B + b] = sigmoid(dot(W[v], x[b]) + bias[v]) for all internal nodes v.
// Block = 256 threads (4 waves). Each wave computes 2 rows -> 8 rows/block.
// x (B*DM*4 = 32 KB) staged in LDS once per block.
__global__ __launch_bounds__(256) void hsm_logits_kernel(
    const float* __restrict__ x,     // [B][DM]
    const float* __restrict__ W,     // [NNODES][DM]
    const float* __restrict__ bias,  // [NNODES]
    float* __restrict__ sig)         // [NNODES][B]
{
    __shared__ float4 xs[B * DM / 4];  // 2048 float4 = 32 KB

    const float4* x4 = (const float4*)x;
    for (int i = threadIdx.x; i < B * DM / 4; i += 256) xs[i] = x4[i];
    __syncthreads();

    const int wave = threadIdx.x >> 6;
    const int lane = threadIdx.x & 63;
    const int row0 = (blockIdx.x * 4 + wave) * 2;
    if (row0 >= NNODES) return;
    const bool two = (row0 + 1) < NNODES;

    const float4* w0 = (const float4*)(W + (size_t)row0 * DM);
    const float4* w1 = (const float4*)(W + (size_t)(two ? row0 + 1 : row0) * DM);

    float acc0[B], acc1[B];
    #pragma unroll
    for (int b = 0; b < B; b++) { acc0[b] = 0.f; acc1[b] = 0.f; }

    // DM = 1024 floats = 256 float4 per row; 64 lanes x 4 iterations.
    #pragma unroll
    for (int k = 0; k < 4; k++) {
        const float4 a = w0[k * 64 + lane];
        const float4 c = w1[k * 64 + lane];
        #pragma unroll
        for (int b = 0; b < B; b++) {
            const float4 xv = xs[b * (DM / 4) + k * 64 + lane];
            acc0[b] += a.x * xv.x + a.y * xv.y + a.z * xv.z + a.w * xv.w;
            acc1[b] += c.x * xv.x + c.y * xv.y + c.z * xv.z + c.w * xv.w;
        }
    }

    // Wave-level tree reduction across 64 lanes.
    #pragma unroll
    for (int off = 32; off > 0; off >>= 1) {
        #pragma unroll
        for (int b = 0; b < B; b++) {
            acc0[b] += __shfl_down(acc0[b], off, 64);
            acc1[b] += __shfl_down(acc1[b], off, 64);
        }
    }

    if (lane == 0) {
        const float bb0 = bias[row0];
        #pragma unroll
        for (int b = 0; b < B; b++) {
            const float z = acc0[b] + bb0;
            sig[(size_t)row0 * B + b] = 1.f / (1.f + expf(-z));
        }
        if (two) {
            const float bb1 = bias[row0 + 1];
            #pragma unroll
            for (int b = 0; b < B; b++) {
                const float z = acc1[b] + bb1;
                sig[(size_t)(row0 + 1) * B + b] = 1.f / (1.f + expf(-z));
            }
        }
    }
}

// Kernel 2: out[b*T + t] = prod_{d} sig[paths[ids[b][t]][d] * B + b]
__global__ __launch_bounds__(256) void hsm_prod_kernel(
    const int* __restrict__ ids,    // [B][T]
    const int* __restrict__ paths,  // [V][D]
    const float* __restrict__ sig,  // [NNODES][B]
    float* __restrict__ out)        // [B][T]
{
    const int i = blockIdx.x * blockDim.x + threadIdx.x;
    if (i >= B * T) return;
    const int b = i / T;
    const int id = ids[i];
    const int* p = paths + (size_t)id * D;
    float prod = 1.f;
    #pragma unroll
    for (int d = 0; d < D; d++) {
        prod *= sig[(size_t)p[d] * B + b];
    }
    out[i] = prod;
}

extern "C" void kernel_launch(void* const* d_in, const int* in_sizes, int n_in,
                              void* d_out, int out_size, void* d_ws, size_t ws_size,
                              hipStream_t stream) {
    const float* x     = (const float*)d_in[0];  // [B, DM]
    const int*   ids   = (const int*)d_in[1];    // [B, T]
    const int*   paths = (const int*)d_in[2];    // [V, D]
    const float* W     = (const float*)d_in[3];  // [NNODES, DM]
    const float* bias  = (const float*)d_in[4];  // [NNODES]
    float* out = (float*)d_out;                  // [B, T]
    float* sig = (float*)d_ws;                   // [NNODES, B] = 1 MB scratch

    const int rows_per_block = 8;  // 4 waves x 2 rows
    const int grid1 = (NNODES + rows_per_block - 1) / rows_per_block;  // 4096
    hsm_logits_kernel<<<grid1, 256, 0, stream>>>(x, W, bias, sig);

    const int grid2 = (B * T + 255) / 256;  // 32
    hsm_prod_kernel<<<grid2, 256, 0, stream>>>(ids, paths, sig, out);
}